// Round 2
// baseline (457.472 us; speedup 1.0000x reference)
//
#include <hip/hip_runtime.h>
#include <math.h>
#include <float.h>

// Problem constants (fixed shapes from setup_inputs)
constexpr int TOPK = 8;
constexpr int NUM_SPECIAL = 999;
constexpr int V = 30522;
constexpr int D = 768;
constexpr int BLOCK = 256;
constexpr int V2 = V / 2;          // 15261 float2 per row (V even, rows 8B-aligned)
constexpr int CAP = 512;           // candidate buffer bound (ties safety)

// Monotone map float -> uint32 (order-preserving), packed with ~idx so that
// larger key == (larger value, then SMALLER index) -- matches jax.lax.top_k
// tie-breaking (lower index first among equal values).
__device__ __forceinline__ unsigned long long fkey(float v, unsigned int idx) {
    unsigned int u = __float_as_uint(v);
    u = ((int)u < 0) ? ~u : (u | 0x80000000u);
    return ((unsigned long long)u << 32) | (unsigned long long)(~idx);
}

__global__ __launch_bounds__(BLOCK) void dvat_kernel(
    const float* __restrict__ delta_grad,   // [B,S,D]
    const float* __restrict__ src_embeds,   // [B,S,D]
    const float* __restrict__ emb,          // [V,D]
    const int*   __restrict__ src_tokens,   // [B,S]
    const float* __restrict__ pred_lm,      // [B,S,V]
    const int*   __restrict__ attn,         // [B,S]
    const float* __restrict__ rand_u,       // [B,S]
    int* __restrict__ out)                  // [B,S]
{
    const int pos = blockIdx.x;        // b*S + s
    const int tid = threadIdx.x;
    const int lane = tid & 63;
    const int wave = tid >> 6;

    __shared__ float sh_vals[BLOCK * TOPK];          // 8 KB; later aliased for dg/se rows
    __shared__ unsigned long long sh_cand64[CAP];    // 4 KB
    __shared__ int    s_ncand;
    __shared__ float  s_g8;
    __shared__ int    s_cand[TOPK];
    __shared__ double s_scores[TOPK];
    __shared__ double s_pd[4], s_ssq[4];

    // ---------------- Pass 1: branchless per-thread top-8 VALUES ------------
    // Two independent sorted-insert networks (x/y of float2) to cut the serial
    // dependency chain; no branches -> no any-lane predication tax, no u64 ops.
    const float2* row2 = (const float2*)(pred_lm + (size_t)pos * V);

    float vx[TOPK], vy[TOPK];
    #pragma unroll
    for (int j = 0; j < TOPK; ++j) { vx[j] = -INFINITY; vy[j] = -INFINITY; }

    for (int i = tid; i < V2; i += BLOCK) {
        float2 f = row2[i];
        float t = f.x;
        #pragma unroll
        for (int j = 0; j < TOPK; ++j) {
            float m = fmaxf(vx[j], t); t = fminf(vx[j], t); vx[j] = m;
        }
        t = f.y;
        #pragma unroll
        for (int j = 0; j < TOPK; ++j) {
            float m = fmaxf(vy[j], t); t = fminf(vy[j], t); vy[j] = m;
        }
    }
    // bitonic half-merge: top-8 multiset of the two sorted-desc 8-lists
    float v8[TOPK];
    #pragma unroll
    for (int j = 0; j < TOPK; ++j) v8[j] = fmaxf(vx[j], vy[TOPK - 1 - j]);

    // transposed dump -> conflict-free LDS writes
    #pragma unroll
    for (int j = 0; j < TOPK; ++j) sh_vals[j * BLOCK + tid] = v8[j];
    __syncthreads();

    // ---------------- g8 = exact 8th-largest value of the row ---------------
    // 8 rounds of wave-0 max-extract over the 2048 dumped values (multiset).
    for (int it = 0; it < TOPK; ++it) {
        if (tid < 64) {
            float m = -INFINITY; int ms = 0;
            for (int j = tid; j < BLOCK * TOPK; j += 64) {
                float x = sh_vals[j];
                if (x > m) { m = x; ms = j; }
            }
            #pragma unroll
            for (int off = 32; off; off >>= 1) {
                float om = __shfl_down(m, off, 64);
                int   os = __shfl_down(ms, off, 64);
                if (om > m) { m = om; ms = os; }
            }
            if (tid == 0) {
                sh_vals[ms] = -INFINITY;          // remove one occurrence
                if (it == TOPK - 1) s_g8 = m;
            }
        }
        __syncthreads();
    }

    // ---------------- Pass 2: index recovery (re-read hits L2/L3) -----------
    if (tid == 0) s_ncand = 0;
    __syncthreads();
    const float g8 = s_g8;
    for (int i = tid; i < V2; i += BLOCK) {
        float2 f = row2[i];
        if (f.x >= g8) {
            int p = atomicAdd(&s_ncand, 1);
            if (p < CAP) sh_cand64[p] = fkey(f.x, (unsigned)(2 * i));
        }
        if (f.y >= g8) {
            int p = atomicAdd(&s_ncand, 1);
            if (p < CAP) sh_cand64[p] = fkey(f.y, (unsigned)(2 * i + 1));
        }
    }
    __syncthreads();
    const int ncand = min(s_ncand, CAP);   // >= 8 by construction

    // ---------------- exact top-8 (value desc, index asc) from candidates ---
    for (int it = 0; it < TOPK; ++it) {
        if (tid < 64) {
            unsigned long long m = 0ull; int ms = 0;
            for (int j = tid; j < ncand; j += 64) {
                unsigned long long x = sh_cand64[j];
                if (x > m) { m = x; ms = j; }
            }
            #pragma unroll
            for (int off = 32; off; off >>= 1) {
                unsigned long long om = __shfl_down(m, off, 64);
                int os = __shfl_down(ms, off, 64);
                if (om > m) { m = om; ms = os; }
            }
            if (tid == 0) {
                s_cand[it] = (m == 0ull) ? 0 : (int)(~(unsigned int)m);
                sh_cand64[ms] = 0ull;
            }
        }
        __syncthreads();
    }

    // topk_idx *= attention_mask  (mask==0 -> all candidates index 0)
    if (tid == 0 && attn[pos] == 0) {
        #pragma unroll
        for (int k = 0; k < TOPK; ++k) s_cand[k] = 0;
    }
    __syncthreads();

    // ---------------- stage dg/se rows in LDS + prev_dot/src_sq -------------
    float* shf = sh_vals;   // reuse: [0..D) = delta_grad row, [D..2D) = src_embeds
    const float* dg = delta_grad + (size_t)pos * D;
    const float* se = src_embeds + (size_t)pos * D;

    double pd = 0.0, ssq = 0.0;
    for (int i = tid; i < D; i += BLOCK) {
        float g = dg[i], e = se[i];
        shf[i] = g;
        shf[D + i] = e;
        pd  += (double)g * (double)e;
        ssq += (double)e * (double)e;
    }
    #pragma unroll
    for (int off = 32; off; off >>= 1) {
        pd  += __shfl_down(pd, off, 64);
        ssq += __shfl_down(ssq, off, 64);
    }
    if (lane == 0) { s_pd[wave] = pd; s_ssq[wave] = ssq; }
    __syncthreads();

    const double prev_dot = s_pd[0] + s_pd[1] + s_pd[2] + s_pd[3];
    const double src_sq   = s_ssq[0] + s_ssq[1] + s_ssq[2] + s_ssq[3];

    // ---------------- score 8 candidates (2 per wave, fp64) -----------------
    #pragma unroll
    for (int kk = 0; kk < 2; ++kk) {
        const int k = 2 * wave + kk;
        const int v = s_cand[k];
        const float* ev = emb + (size_t)v * D;
        double ddg = 0.0, dse = 0.0, dvv = 0.0;
        for (int i = lane; i < D; i += 64) {
            double e = (double)ev[i];
            ddg += e * (double)shf[i];
            dse += e * (double)shf[D + i];
            dvv += e * e;
        }
        #pragma unroll
        for (int off = 32; off; off >>= 1) {
            ddg += __shfl_down(ddg, off, 64);
            dse += __shfl_down(dse, off, 64);
            dvv += __shfl_down(dvv, off, 64);
        }
        if (lane == 0) {
            double sq = src_sq + dvv - 2.0 * dse;
            if (sq < 0.0) sq = 0.0;
            double dn = sqrt(sq + 1e-20);
            s_scores[k] = (ddg - prev_dot) / dn;   // dir_dot_grad / dir_norm
        }
    }
    __syncthreads();

    // ---------------- filtered argmax + swap blend (thread 0) ---------------
    if (tid == 0) {
        const int src_tok = src_tokens[pos];
        int best = 0;
        double best_s = 0.0;
        bool found = false;
        #pragma unroll
        for (int k = 0; k < TOPK; ++k) {
            const int v = s_cand[k];
            if (v < NUM_SPECIAL || v == src_tok) continue;   // -inf in reference
            const double sc = s_scores[k];
            // jnp.argmax: lowest index wins ties
            if (!found || sc > best_s || (sc == best_s && v < best)) {
                best = v; best_s = sc; found = true;
            }
        }
        const int adv_flip = found ? best : 0;   // argmax of all -inf -> 0
        const bool no_special = (src_tok >= NUM_SPECIAL);
        const bool swap = (rand_u[pos] > 0.7f);  // 1.0 - SWAP_RATIO in f32
        out[pos] = (no_special && swap) ? adv_flip : src_tok;
    }
}

extern "C" void kernel_launch(void* const* d_in, const int* in_sizes, int n_in,
                              void* d_out, int out_size, void* d_ws, size_t ws_size,
                              hipStream_t stream) {
    const float* delta_grad = (const float*)d_in[0];
    const float* src_embeds = (const float*)d_in[1];
    const float* emb        = (const float*)d_in[2];
    const int*   src_tokens = (const int*)d_in[3];
    const float* pred_lm    = (const float*)d_in[4];
    const int*   attn       = (const int*)d_in[5];
    const float* randu      = (const float*)d_in[6];
    int* out = (int*)d_out;

    const int BS = in_sizes[3];   // B*S = 2048 positions
    dvat_kernel<<<BS, BLOCK, 0, stream>>>(delta_grad, src_embeds, emb,
                                          src_tokens, pred_lm, attn, randu, out);
}

// Round 3
// 413.982 us; speedup vs baseline: 1.1051x; 1.1051x over previous
//
#include <hip/hip_runtime.h>
#include <math.h>

// Problem constants (fixed shapes from setup_inputs)
constexpr int TOPK = 8;
constexpr int NUM_SPECIAL = 999;
constexpr int V = 30522;
constexpr int D = 768;
constexpr int BLOCK = 256;
constexpr int V2 = V / 2;                      // 15261 float2 per row
constexpr int NQ = 14;                         // full quad rounds: 14*1024 = 14336
constexpr int NK = (V2 + BLOCK - 1) / BLOCK;   // 60 float2 per thread stream
constexpr int CAP = 512;                       // candidate buffer (ties safety)
constexpr int HOTCAP = 64;                     // hot-thread list bound

// Monotone map float -> uint32 (order-preserving), packed with ~idx so that
// larger key == (larger value, then SMALLER index) -- matches jax.lax.top_k
// tie-breaking (lower index first among equal values).
__device__ __forceinline__ unsigned long long fkey(float v, unsigned int idx) {
    unsigned int u = __float_as_uint(v);
    u = ((int)u < 0) ? ~u : (u | 0x80000000u);
    return ((unsigned long long)u << 32) | (unsigned long long)(~idx);
}

// branchless sorted-desc top-8 insert (2 VALU per stage: v_max/v_min)
__device__ __forceinline__ void net8(float (&L)[TOPK], float t) {
    #pragma unroll
    for (int j = 0; j < TOPK; ++j) {
        float m = fmaxf(L[j], t); t = fminf(L[j], t); L[j] = m;
    }
}

__device__ __forceinline__ void cmpx(float& a, float& b) {  // desc compare-exchange
    float m = fmaxf(a, b), n = fminf(a, b); a = m; b = n;
}
// sort a bitonic 8-sequence descending (bitonic merge network)
__device__ __forceinline__ void bitonic_sort8_desc(float (&v)[TOPK]) {
    cmpx(v[0], v[4]); cmpx(v[1], v[5]); cmpx(v[2], v[6]); cmpx(v[3], v[7]);
    cmpx(v[0], v[2]); cmpx(v[1], v[3]); cmpx(v[4], v[6]); cmpx(v[5], v[7]);
    cmpx(v[0], v[1]); cmpx(v[2], v[3]); cmpx(v[4], v[5]); cmpx(v[6], v[7]);
}

// Per-wave exact top-8 extraction from 64 sorted-desc 8-lists (pops heads).
// Deterministic tie-break by lane id. lane 0 writes the 8 values to dst[0..8).
__device__ __forceinline__ void wave_extract8(float (&cur)[TOPK], int lane,
                                              float* dst) {
    #pragma unroll
    for (int r = 0; r < TOPK; ++r) {
        float m = cur[0];
        int ml = lane;
        #pragma unroll
        for (int off = 1; off < 64; off <<= 1) {
            float om = __shfl_xor(m, off, 64);
            int   ol = __shfl_xor(ml, off, 64);
            if (om > m || (om == m && ol < ml)) { m = om; ml = ol; }
        }
        if (lane == ml) {                      // winner pops its head
            #pragma unroll
            for (int j = 0; j < TOPK - 1; ++j) cur[j] = cur[j + 1];
            cur[TOPK - 1] = -INFINITY;
        }
        if (lane == 0) dst[r] = m;
    }
}

__global__ __launch_bounds__(BLOCK, 8) void dvat_kernel(
    const float* __restrict__ delta_grad,   // [B,S,D]
    const float* __restrict__ src_embeds,   // [B,S,D]
    const float* __restrict__ emb,          // [V,D]
    const int*   __restrict__ src_tokens,   // [B,S]
    const float* __restrict__ pred_lm,      // [B,S,V]
    const int*   __restrict__ attn,         // [B,S]
    const float* __restrict__ rand_u,       // [B,S]
    int* __restrict__ out)                  // [B,S]
{
    const int pos = blockIdx.x;        // b*S + s
    const int tid = threadIdx.x;
    const int lane = tid & 63;
    const int wave = tid >> 6;

    __shared__ float  sm32[32];                   // 4 waves x sorted top-8
    __shared__ float  s_g8;
    __shared__ int    s_hot[HOTCAP];
    __shared__ int    s_nhot;
    __shared__ int    s_ncand;
    __shared__ unsigned long long sh_cand64[CAP]; // 4 KB
    __shared__ int    s_cand[TOPK];
    __shared__ double s_scores[TOPK];
    __shared__ double s_pd[4], s_ssq[4];
    __shared__ float  shf[2 * D];                 // dg row | se row (6 KB)

    if (tid == 0) { s_nhot = 0; s_ncand = 0; }

    // ---------------- Pass 1: branchless per-thread top-8 values ------------
    // Quad-unrolled: 4 independent float2 loads in flight per iteration (MLP=4).
    const float2* row2 = (const float2*)(pred_lm + (size_t)pos * V);

    float vx[TOPK], vy[TOPK];
    #pragma unroll
    for (int j = 0; j < TOPK; ++j) { vx[j] = -INFINITY; vy[j] = -INFINITY; }

    int i = tid;
    for (int q = 0; q < NQ; ++q, i += 4 * BLOCK) {
        float2 a = row2[i];
        float2 b = row2[i + BLOCK];
        float2 c = row2[i + 2 * BLOCK];
        float2 d = row2[i + 3 * BLOCK];
        net8(vx, a.x); net8(vy, a.y);
        net8(vx, b.x); net8(vy, b.y);
        net8(vx, c.x); net8(vy, c.y);
        net8(vx, d.x); net8(vy, d.y);
    }
    for (; i < V2; i += BLOCK) {                  // tail: 925 float2
        float2 f = row2[i];
        net8(vx, f.x); net8(vy, f.y);
    }

    // thread's exact top-8 (sorted desc): bitonic half-merge + merge network
    float v8[TOPK];
    #pragma unroll
    for (int j = 0; j < TOPK; ++j) v8[j] = fmaxf(vx[j], vy[TOPK - 1 - j]);
    bitonic_sort8_desc(v8);
    const float tmax = v8[0];                     // thread stream max

    // ---------------- g8 = exact 8th-largest of the row ---------------------
    wave_extract8(v8, lane, &sm32[wave * 8]);     // destroys v8
    __syncthreads();

    if (wave == 0) {                              // top-8 of the 4x8 survivors
        float c = (lane < 32) ? sm32[lane] : -INFINITY;
        float m = -INFINITY;
        #pragma unroll
        for (int r = 0; r < TOPK; ++r) {
            m = c; int ml = lane;
            #pragma unroll
            for (int off = 1; off < 64; off <<= 1) {
                float om = __shfl_xor(m, off, 64);
                int   ol = __shfl_xor(ml, off, 64);
                if (om > m || (om == m && ol < ml)) { m = om; ml = ol; }
            }
            if (lane == ml) c = -INFINITY;        // pop
        }
        if (lane == 0) s_g8 = m;                  // 8th extracted = exact g8
    }
    __syncthreads();
    const float g8 = s_g8;

    // ---------------- sparse index recovery ---------------------------------
    // Only threads whose stream-max >= g8 can hold a top-8 member (<=8 with
    // distinct values). Rescan just those threads' strided positions.
    if (tmax >= g8) {
        int p = atomicAdd(&s_nhot, 1);
        if (p < HOTCAP) s_hot[p] = tid;
    }
    __syncthreads();

    if (s_nhot <= HOTCAP) {
        const int nhot = s_nhot;
        const int total = nhot * NK;
        for (int w = tid; w < total; w += BLOCK) {
            const int h = w / NK;                 // const-div -> magic mul
            const int k = w - h * NK;
            const int i2 = s_hot[h] + (k << 8);   // stride BLOCK in float2 space
            if (i2 < V2) {
                float2 f = row2[i2];
                if (f.x >= g8) {
                    int p = atomicAdd(&s_ncand, 1);
                    if (p < CAP) sh_cand64[p] = fkey(f.x, (unsigned)(2 * i2));
                }
                if (f.y >= g8) {
                    int p = atomicAdd(&s_ncand, 1);
                    if (p < CAP) sh_cand64[p] = fkey(f.y, (unsigned)(2 * i2 + 1));
                }
            }
        }
    } else {                                      // massive-tie fallback: full rescan
        for (int i2 = tid; i2 < V2; i2 += BLOCK) {
            float2 f = row2[i2];
            if (f.x >= g8) {
                int p = atomicAdd(&s_ncand, 1);
                if (p < CAP) sh_cand64[p] = fkey(f.x, (unsigned)(2 * i2));
            }
            if (f.y >= g8) {
                int p = atomicAdd(&s_ncand, 1);
                if (p < CAP) sh_cand64[p] = fkey(f.y, (unsigned)(2 * i2 + 1));
            }
        }
    }
    __syncthreads();
    const int ncand = min(s_ncand, CAP);          // >= 8 by construction

    // ---------------- exact top-8 (value desc, index asc) -------------------
    for (int it = 0; it < TOPK; ++it) {
        if (tid < 64) {
            unsigned long long m = 0ull; int ms = 0;
            for (int j = tid; j < ncand; j += 64) {
                unsigned long long x = sh_cand64[j];
                if (x > m) { m = x; ms = j; }
            }
            #pragma unroll
            for (int off = 32; off; off >>= 1) {
                unsigned long long om = __shfl_down(m, off, 64);
                int os = __shfl_down(ms, off, 64);
                if (om > m) { m = om; ms = os; }
            }
            if (tid == 0) {
                s_cand[it] = (m == 0ull) ? 0 : (int)(~(unsigned int)m);
                sh_cand64[ms] = 0ull;
            }
        }
        __syncthreads();
    }

    // topk_idx *= attention_mask  (mask==0 -> all candidates index 0)
    if (tid == 0 && attn[pos] == 0) {
        #pragma unroll
        for (int k = 0; k < TOPK; ++k) s_cand[k] = 0;
    }
    __syncthreads();

    // ---------------- stage dg/se rows in LDS + prev_dot/src_sq -------------
    const float* dg = delta_grad + (size_t)pos * D;
    const float* se = src_embeds + (size_t)pos * D;

    double pd = 0.0, ssq = 0.0;
    for (int ii = tid; ii < D; ii += BLOCK) {
        float g = dg[ii], e = se[ii];
        shf[ii] = g;
        shf[D + ii] = e;
        pd  += (double)g * (double)e;
        ssq += (double)e * (double)e;
    }
    #pragma unroll
    for (int off = 32; off; off >>= 1) {
        pd  += __shfl_down(pd, off, 64);
        ssq += __shfl_down(ssq, off, 64);
    }
    if (lane == 0) { s_pd[wave] = pd; s_ssq[wave] = ssq; }
    __syncthreads();

    const double prev_dot = s_pd[0] + s_pd[1] + s_pd[2] + s_pd[3];
    const double src_sq   = s_ssq[0] + s_ssq[1] + s_ssq[2] + s_ssq[3];

    // ---------------- score 8 candidates (2 per wave, fp64) -----------------
    #pragma unroll
    for (int kk = 0; kk < 2; ++kk) {
        const int k = 2 * wave + kk;
        const int v = s_cand[k];
        const float* ev = emb + (size_t)v * D;
        double ddg = 0.0, dse = 0.0, dvv = 0.0;
        for (int ii = lane; ii < D; ii += 64) {
            double e = (double)ev[ii];
            ddg += e * (double)shf[ii];
            dse += e * (double)shf[D + ii];
            dvv += e * e;
        }
        #pragma unroll
        for (int off = 32; off; off >>= 1) {
            ddg += __shfl_down(ddg, off, 64);
            dse += __shfl_down(dse, off, 64);
            dvv += __shfl_down(dvv, off, 64);
        }
        if (lane == 0) {
            double sq = src_sq + dvv - 2.0 * dse;
            if (sq < 0.0) sq = 0.0;
            double dn = sqrt(sq + 1e-20);
            s_scores[k] = (ddg - prev_dot) / dn;   // dir_dot_grad / dir_norm
        }
    }
    __syncthreads();

    // ---------------- filtered argmax + swap blend (thread 0) ---------------
    if (tid == 0) {
        const int src_tok = src_tokens[pos];
        int best = 0;
        double best_s = 0.0;
        bool found = false;
        #pragma unroll
        for (int k = 0; k < TOPK; ++k) {
            const int v = s_cand[k];
            if (v < NUM_SPECIAL || v == src_tok) continue;   // -inf in reference
            const double sc = s_scores[k];
            // jnp.argmax: lowest index wins ties
            if (!found || sc > best_s || (sc == best_s && v < best)) {
                best = v; best_s = sc; found = true;
            }
        }
        const int adv_flip = found ? best : 0;   // argmax of all -inf -> 0
        const bool no_special = (src_tok >= NUM_SPECIAL);
        const bool swap = (rand_u[pos] > 0.7f);  // 1.0 - SWAP_RATIO in f32
        out[pos] = (no_special && swap) ? adv_flip : src_tok;
    }
}

extern "C" void kernel_launch(void* const* d_in, const int* in_sizes, int n_in,
                              void* d_out, int out_size, void* d_ws, size_t ws_size,
                              hipStream_t stream) {
    const float* delta_grad = (const float*)d_in[0];
    const float* src_embeds = (const float*)d_in[1];
    const float* emb        = (const float*)d_in[2];
    const int*   src_tokens = (const int*)d_in[3];
    const float* pred_lm    = (const float*)d_in[4];
    const int*   attn       = (const int*)d_in[5];
    const float* randu      = (const float*)d_in[6];
    int* out = (int*)d_out;

    const int BS = in_sizes[3];   // B*S = 2048 positions
    dvat_kernel<<<BS, BLOCK, 0, stream>>>(delta_grad, src_embeds, emb,
                                          src_tokens, pred_lm, attn, randu, out);
}